// Round 1
// baseline (814.111 us; speedup 1.0000x reference)
//
#include <hip/hip_runtime.h>
#include <math.h>

#define B_SZ   16384
#define D_EMB  128
#define D_HID  1024
#define D_FEAT 4096

// ---------------------------------------------------------------------------
// Kernel 1: compute the two gate vectors g[2][D_FEAT] into workspace.
// grid = 2 gates * (D_FEAT/256) blocks, 256 threads each.
// Each block: ctx[128] -> LDS, h[1024] = relu(ctx@W1+b1) -> LDS,
// then each thread computes one gate output j: sigmoid(h@W2[:,j]+b2[j])*2.
// ---------------------------------------------------------------------------
__global__ __launch_bounds__(256) void gate_kernel(
    const float* __restrict__ ctx1, const float* __restrict__ ctx2,
    const float* __restrict__ W1a,  const float* __restrict__ b1a,
    const float* __restrict__ W2a,  const float* __restrict__ b2a,
    const float* __restrict__ W1b,  const float* __restrict__ b1b,
    const float* __restrict__ W2b,  const float* __restrict__ b2b,
    float* __restrict__ gates /* [2][D_FEAT] */)
{
    const int blocks_per_gate = D_FEAT / 256;       // 16
    const int g   = blockIdx.x / blocks_per_gate;   // 0 or 1
    const int blk = blockIdx.x % blocks_per_gate;

    const float* ctx = (g == 0) ? ctx1 : ctx2;
    const float* W1  = (g == 0) ? W1a  : W1b;
    const float* b1  = (g == 0) ? b1a  : b1b;
    const float* W2  = (g == 0) ? W2a  : W2b;
    const float* b2  = (g == 0) ? b2a  : b2b;

    __shared__ float s_ctx[D_EMB];
    __shared__ float s_h[D_HID];

    const int t = threadIdx.x;
    if (t < D_EMB) s_ctx[t] = ctx[t];
    __syncthreads();

    // Stage 1: h = relu(ctx @ W1 + b1). W1 is [D_EMB, D_HID] row-major,
    // so for fixed i, consecutive threads read consecutive W1 entries.
#pragma unroll
    for (int r = 0; r < D_HID / 256; ++r) {         // 4 h-values per thread
        const int m = t + 256 * r;
        float acc = b1[m];
#pragma unroll 8
        for (int i = 0; i < D_EMB; ++i)
            acc = fmaf(s_ctx[i], W1[i * D_HID + m], acc);
        s_h[m] = acc > 0.0f ? acc : 0.0f;
    }
    __syncthreads();

    // Stage 2: one gate output per thread. W2 is [D_HID, D_FEAT] row-major:
    // consecutive threads (consecutive j) read consecutive addresses. s_h[k]
    // is a wave-uniform broadcast (conflict-free).
    const int j = blk * 256 + t;
    float acc = b2[j];
#pragma unroll 8
    for (int k = 0; k < D_HID; ++k)
        acc = fmaf(s_h[k], W2[k * D_FEAT + j], acc);

    const float gval = 2.0f / (1.0f + expf(-acc));
    gates[g * D_FEAT + j] = gval;
}

// ---------------------------------------------------------------------------
// Kernel 2: out1 = emb * g1 (broadcast over rows), out2 = emb * g2.
// One float4 per thread; gates (32 KB) stay hot in L1/L2.
// ---------------------------------------------------------------------------
__global__ __launch_bounds__(256) void mul_kernel(
    const float4* __restrict__ emb,
    const float4* __restrict__ gates,   // [2][D_FEAT/4]
    float4* __restrict__ out1,
    float4* __restrict__ out2)
{
    const int idx = blockIdx.x * blockDim.x + threadIdx.x;
    const int total = B_SZ * D_FEAT / 4;
    if (idx >= total) return;

    const int jg = idx & (D_FEAT / 4 - 1);   // column float4 index

    const float4 e  = emb[idx];
    const float4 g1 = gates[jg];
    const float4 g2 = gates[D_FEAT / 4 + jg];

    float4 o1, o2;
    o1.x = e.x * g1.x; o1.y = e.y * g1.y; o1.z = e.z * g1.z; o1.w = e.w * g1.w;
    o2.x = e.x * g2.x; o2.y = e.y * g2.y; o2.z = e.z * g2.z; o2.w = e.w * g2.w;

    out1[idx] = o1;
    out2[idx] = o2;
}

extern "C" void kernel_launch(void* const* d_in, const int* in_sizes, int n_in,
                              void* d_out, int out_size, void* d_ws, size_t ws_size,
                              hipStream_t stream)
{
    // Input order (setup_inputs dict order):
    // 0 flat_emb [B, D_FEAT]
    // 1 fs1_ctx_bias [1, D_EMB]   2 fs2_ctx_bias [1, D_EMB]
    // 3 fs1_W1 [D_EMB, D_HID]     4 fs1_b1 [D_HID]
    // 5 fs1_W2 [D_HID, D_FEAT]    6 fs1_b2 [D_FEAT]
    // 7 fs2_W1                    8 fs2_b1
    // 9 fs2_W2                   10 fs2_b2
    const float* flat_emb = (const float*)d_in[0];
    const float* ctx1     = (const float*)d_in[1];
    const float* ctx2     = (const float*)d_in[2];
    const float* W1a      = (const float*)d_in[3];
    const float* b1a      = (const float*)d_in[4];
    const float* W2a      = (const float*)d_in[5];
    const float* b2a      = (const float*)d_in[6];
    const float* W1b      = (const float*)d_in[7];
    const float* b1b      = (const float*)d_in[8];
    const float* W2b      = (const float*)d_in[9];
    const float* b2b      = (const float*)d_in[10];

    float* out1  = (float*)d_out;                       // [B, D_FEAT]
    float* out2  = (float*)d_out + (size_t)B_SZ * D_FEAT;
    float* gates = (float*)d_ws;                        // [2][D_FEAT] = 32 KB

    // Kernel 1: gates (tiny). Same-stream ordering guarantees completion
    // before kernel 2 reads them.
    gate_kernel<<<2 * (D_FEAT / 256), 256, 0, stream>>>(
        ctx1, ctx2, W1a, b1a, W2a, b2a, W1b, b1b, W2b, b2b, gates);

    // Kernel 2: broadcast multiply, one float4 per thread.
    const int total4 = B_SZ * D_FEAT / 4;               // 16,777,216
    mul_kernel<<<total4 / 256, 256, 0, stream>>>(
        (const float4*)flat_emb, (const float4*)gates,
        (float4*)out1, (float4*)out2);
}